// Round 1
// 143.370 us; speedup vs baseline: 1.0163x; 1.0163x over previous
//
#include <hip/hip_runtime.h>
#include <math.h>

// Problem constants: B=64, N=512, d=64
#define NB 64
#define NN 512
#define ND 64

#define LOG2E 1.4426950408889634f
#define LN2   0.6931471805599453f
#define RING  16                      // prefetch ring depth (columns in flight)
#define SD    592                     // padded step count per wave plane (576 + RING)
#define NINF  __int_as_float(0xFF800000u)   // -inf

typedef __attribute__((ext_vector_type(8))) short  bf16x8;  // 8 bf16 in 4 VGPRs
typedef __attribute__((ext_vector_type(4))) float  f32x4;

// fp32 -> bf16 bits, round-to-nearest-even (inputs are finite)
static __device__ __forceinline__ unsigned short f2bf(float f) {
    unsigned u = __float_as_uint(f);
    u += 0x7FFFu + ((u >> 16) & 1u);
    return (unsigned short)(u >> 16);
}

// ---------------------------------------------------------------------------
// Kernel 0 (pack): X,Y (f32 row-major) -> bf16 in MFMA-fragment order, plus
// fp32 row norms (R12/R13-proven, unchanged).
// ---------------------------------------------------------------------------
__global__ __launch_bounds__(256) void pack_kernel(const float* __restrict__ X,
                                                   const float* __restrict__ Y,
                                                   unsigned short* __restrict__ Xp,
                                                   unsigned short* __restrict__ Yp,
                                                   float* __restrict__ nx,
                                                   float* __restrict__ ny) {
    const int gid = blockIdx.x * 256 + threadIdx.x;   // row id, 0..NB*NN-1
    const float* src;
    unsigned short* dst;
    float* ndst;
    if (blockIdx.y == 0) { src = X + (size_t)gid * ND; dst = Xp; ndst = nx; }
    else                 { src = Y + (size_t)gid * ND; dst = Yp; ndst = ny; }

    float v[ND];
    float s = 0.f;
    #pragma unroll
    for (int k = 0; k < ND; k += 4) {
        float4 f = *(const float4*)(src + k);
        v[k] = f.x; v[k + 1] = f.y; v[k + 2] = f.z; v[k + 3] = f.w;
        s += f.x * f.x + f.y * f.y + f.z * f.z + f.w * f.w;
    }
    ndst[gid] = s;

    const int b  = gid >> 9;
    const int i  = gid & 511;
    const int it = i >> 4;             // 16-row tile
    const int lm = i & 15;             // row within tile
    #pragma unroll
    for (int h = 0; h < 2; ++h) {
        #pragma unroll
        for (int q = 0; q < 4; ++q) {
            unsigned w[4];
            #pragma unroll
            for (int m = 0; m < 4; ++m) {
                const int c = h * 32 + q * 8 + 2 * m;
                w[m] = (unsigned)f2bf(v[c]) | ((unsigned)f2bf(v[c + 1]) << 16);
            }
            uint4 pkt; pkt.x = w[0]; pkt.y = w[1]; pkt.z = w[2]; pkt.w = w[3];
            *(uint4*)(dst + ((((size_t)b * 32 + it) * 2 + h) << 9)
                          + (size_t)(q * 16 + lm) * 8) = pkt;
        }
    }
}

// ---------------------------------------------------------------------------
// Kernel 1 (MFMA): W[b][i][j] = bf16( exp2(16 - log2e*||X[b][i]-Y[b][j]||) )
// NEW (R14): output stored in ANTI-DIAGONAL-MAJOR layout Wd[b][w][s][t]
// (uint2 = 4 bf16 rows j0..j0+3, j0 = w*256+4t, column c = i+1, step
// s = i + t), which is exactly the per-lane consumption order of the DP
// kernel. This turns dtw's ring refill from a 64-line scatter into a fully
// coalesced 512B/wave load. Math identical to R13 (absmax 0.0 preserved).
// ---------------------------------------------------------------------------
__global__ __launch_bounds__(256) void cdist_kernel(const unsigned short* __restrict__ Xp,
                                                    const unsigned short* __restrict__ Yp,
                                                    const float* __restrict__ nx,
                                                    const float* __restrict__ ny,
                                                    uint2* __restrict__ Wd) {
    const int b  = blockIdx.z;
    const int ib = blockIdx.x * 128;   // i base (X rows)
    const int jb = blockIdx.y * 128;   // j base (Y rows)
    const int t  = threadIdx.x;

    const int wave = t >> 6;
    const int wi   = (wave & 1) * 64;   // i offset of this wave's 64x64 tile
    const int wj   = (wave >> 1) * 64;  // j offset
    const int lane = t & 63;
    const int lm   = lane & 15;
    const int quad = lane >> 4;

    f32x4 acc[4][4];
    #pragma unroll
    for (int mt = 0; mt < 4; ++mt)
        #pragma unroll
        for (int nt = 0; nt < 4; ++nt)
            acc[mt][nt] = (f32x4){0.f, 0.f, 0.f, 0.f};

    const int jt0 = (jb + wj) >> 4;    // Y tile base
    const int it0 = (ib + wi) >> 4;    // X tile base

    #pragma unroll
    for (int h = 0; h < 2; ++h) {
        bf16x8 Af[4], Bf[4];
        #pragma unroll
        for (int mt = 0; mt < 4; ++mt)   // A from Y tiles (m = j dim)
            Af[mt] = *(const bf16x8*)(Yp
                + ((((size_t)b * 32 + jt0 + mt) * 2 + h) << 9) + (size_t)lane * 8);
        #pragma unroll
        for (int nt = 0; nt < 4; ++nt)   // B from X tiles (n = i dim)
            Bf[nt] = *(const bf16x8*)(Xp
                + ((((size_t)b * 32 + it0 + nt) * 2 + h) << 9) + (size_t)lane * 8);
        #pragma unroll
        for (int mt = 0; mt < 4; ++mt)
            #pragma unroll
            for (int nt = 0; nt < 4; ++nt)
                acc[mt][nt] = __builtin_amdgcn_mfma_f32_16x16x32_bf16(
                    Af[mt], Bf[nt], acc[mt][nt], 0, 0, 0);
    }

    float nxv[4];
    float4 nyv[4];
    #pragma unroll
    for (int nt = 0; nt < 4; ++nt)
        nxv[nt] = nx[(size_t)b * NN + ib + wi + nt * 16 + lm];
    #pragma unroll
    for (int mt = 0; mt < 4; ++mt)
        nyv[mt] = *(const float4*)(ny + (size_t)b * NN + jb + wj + mt * 16 + quad * 4);

    #pragma unroll
    for (int nt = 0; nt < 4; ++nt) {
        const int i = ib + wi + nt * 16 + lm;        // column index c-1
        #pragma unroll
        for (int mt = 0; mt < 4; ++mt) {
            const int j0 = jb + wj + mt * 16 + quad * 4;  // first of 4 rows
            const int wv = j0 >> 8;                   // DP wave (0: j<256)
            const int tt = (j0 >> 2) & 63;            // DP lane
            const float* nyp = (const float*)&nyv[mt];
            unsigned a[4];
            #pragma unroll
            for (int r = 0; r < 4; ++r) {
                float d2 = nyp[r] + nxv[nt] - 2.0f * acc[mt][nt][r];
                float w  = __builtin_amdgcn_exp2f(16.0f - LOG2E * sqrtf(fmaxf(d2, 0.f)));
                a[r] = __float_as_uint(w) + 0x8000u;   // round-half-up to bf16
            }
            uint2 pkt;
            pkt.x = (a[0] >> 16) | (a[1] & 0xFFFF0000u);
            pkt.y = (a[2] >> 16) | (a[3] & 0xFFFF0000u);
            // step s = i + tt; cells with c outside [1,512] are never written
            // and only ever consumed under the guarded (act==false) path.
            Wd[((size_t)(b * 2 + wv) * SD + (size_t)(i + tt)) * 64 + tt] = pkt;
        }
    }
}

// ---------------------------------------------------------------------------
// Kernel 2: soft-DTW DP, exp-domain chain (R11-R13-proven math), two
// pipelined waves per batch, 4 rows/lane. R14 change: W is consumed from
// the anti-diagonal-major layout Wd[b][wave][s][lane] so every ring refill
// is one coalesced 512B wave load (was: 64-line scatter). Column clamping
// is gone — address depends only on (s, lane) and is always in-bounds;
// out-of-range cells hold garbage but are consumed only when act==false.
// ---------------------------------------------------------------------------
static __device__ __forceinline__ float dpp_shr1(float x, float old) {
    return __int_as_float(__builtin_amdgcn_update_dpp(
        __float_as_int(old), __float_as_int(x), 0x138, 0xf, 0xf, false));
}
static __device__ __forceinline__ float dpp_shl1(float x) {
    return __int_as_float(__builtin_amdgcn_update_dpp(
        0, __float_as_int(x), 0x130, 0xf, 0xf, false));
}

static __device__ __forceinline__ void dtw_step4(
    bool W1, bool DOACT, bool DOGUARD, bool DOREN,
    int ss, int u, int t, const uint2* __restrict__ Wdw,
    uint2* ring, float* L, float& diagHold, float& h, float& Otf,
    float& hbuf, float* __restrict__ h0)
{
    // intra-wave handoff: lane t gets lane t-1's h (lane 0: -inf)
    float recvH = dpp_shr1(h, NINF);
    if (W1) {
        recvH = (t == 0) ? hbuf : recvH;   // lane 0: cross-wave value from LDS
        hbuf  = dpp_shl1(hbuf);            // rotate: next step's value to lane 0
    }
    if (DOACT) { if (ss == t && (t > 0 || W1)) Otf = -recvH; }  // adopt scale

    const float up0   = __builtin_amdgcn_exp2f(fminf(recvH + Otf, 80.0f));
    const float diag0 = diagHold;          // 2^16 * F[row ib][j-1], stored dom.
    diagHold = up0 * 65536.0f;             // 2^16 * F[row ib][j] for next step

    const int j = ss - t + 1;
    const uint2 c = ring[u];

    // refill slot u for step ss+RING (coalesced: 64 lanes read 512B run)
    ring[u] = Wdw[(size_t)(ss + RING) * 64];

    bool act = true;
    if (DOGUARD) act = (j >= 1) && (j <= NN);
    if (act) {
        float dd[4];                       // bf16 -> f32: shl/and, exact
        dd[0] = __uint_as_float(c.x << 16);
        dd[1] = __uint_as_float(c.x & 0xFFFF0000u);
        dd[2] = __uint_as_float(c.y << 16);
        dd[3] = __uint_as_float(c.y & 0xFFFF0000u);

        float pre[4], cc[4];
        pre[0] = diag0 + L[0];
        #pragma unroll
        for (int k = 1; k < 4; ++k)
            pre[k] = fmaf(65536.0f, L[k - 1], L[k]);
        #pragma unroll
        for (int k = 0; k < 4; ++k) cc[k] = dd[k] * pre[k];
        float r = up0;
        #pragma unroll
        for (int k = 0; k < 4; ++k) {      // serial chain: 4 fma
            r = fmaf(dd[k], r, cc[k]);
            L[k] = r;
        }

        if (DOREN) {   // branchless full normalization: max(L) -> [1,2)
            float m4 = fmaxf(fmaxf(L[0], L[1]), fmaxf(L[2], L[3]));
            const int   e  = (int)(__float_as_uint(m4) >> 23) - 127;
            const float sc = __uint_as_float((unsigned)(127 - e) << 23); // 2^-e
            #pragma unroll
            for (int k = 0; k < 4; ++k) L[k] *= sc;
            diagHold *= sc;
            Otf -= (float)e;
        }

        h = __builtin_amdgcn_logf(L[3]) - Otf;   // absolute log2-domain handoff
        if (!W1) h0[j] = h;                // publish row-boundary value
    }
}

static __device__ __forceinline__ void run_chunk(
    bool W1, bool ACT, bool GUARD, int base,
    int t, const uint2* __restrict__ Wdw,
    uint2* ring, float* L, float& diagHold, float& h, float& Otf,
    float& hbuf, float* __restrict__ h0)
{
    for (int sb = 0; sb < 64; sb += RING)
        #pragma unroll
        for (int u = 0; u < RING; ++u)
            dtw_step4(W1, ACT, GUARD, (u & 1) == 1,
                      base + sb + u, u, t, Wdw, ring, L,
                      diagHold, h, Otf, hbuf, h0);
}

__global__ __launch_bounds__(128) void dtw_kernel(const uint2* __restrict__ Wd,
                                                  float* __restrict__ out) {
    __shared__ float h0[584];
    const int b    = blockIdx.x;
    const int tid  = threadIdx.x;
    const int t    = tid & 63;
    const int wave = tid >> 6;
    // this lane's column of the anti-diagonal-major plane
    const uint2* __restrict__ Wdw = Wd + ((size_t)(b * 2 + wave) * SD) * 64 + t;

    float L[4] = {0.f, 0.f, 0.f, 0.f};     // F(boundary) = 0
    float diagHold = (wave == 0 && t == 0) ? 65536.0f : 0.0f; // 2^16*F[0][0]
    float h = NINF, Otf = 0.0f, hbuf = NINF;

    uint2 ring[RING];
    #pragma unroll
    for (int u = 0; u < RING; ++u)
        ring[u] = Wdw[(size_t)u * 64];     // payload for step u (dead if OOB)

    for (int wall = 0; wall < 11; ++wall) {
        const int ch = wave ? wall - 2 : wall;   // wave 1 lags 2 chunks
        if (wave == 0) {
            if (ch == 0)
                run_chunk(false, true,  true,  0,      t, Wdw, ring, L, diagHold, h, Otf, hbuf, h0);
            else if (ch >= 1 && ch <= 7)
                run_chunk(false, false, false, ch*64,  t, Wdw, ring, L, diagHold, h, Otf, hbuf, h0);
            else if (ch == 8)
                run_chunk(false, false, true,  512,    t, Wdw, ring, L, diagHold, h, Otf, hbuf, h0);
        } else {
            if (ch == 0)
                run_chunk(true,  true,  true,  0,      t, Wdw, ring, L, diagHold, h, Otf, hbuf, h0);
            else if (ch >= 1 && ch <= 7)
                run_chunk(true,  false, false, ch*64,  t, Wdw, ring, L, diagHold, h, Otf, hbuf, h0);
            else if (ch == 8)
                run_chunk(true,  false, true,  512,    t, Wdw, ring, L, diagHold, h, Otf, hbuf, h0);
        }
        __syncthreads();
        // preload wave 1's next-chunk boundary values (cols base+1..base+64)
        if (wave && wall >= 1 && wall <= 9)
            hbuf = h0[(wall - 1) * 64 + 1 + t];
    }

    // F[512][512] = 2^(16*1024) e^{-R}; h = log2 F (absolute)
    if (wave == 1 && t == 63) out[b] = (16384.0f - h) * LN2;
}

extern "C" void kernel_launch(void* const* d_in, const int* in_sizes, int n_in,
                              void* d_out, int out_size, void* d_ws, size_t ws_size,
                              hipStream_t stream) {
    const float* X = (const float*)d_in[0];
    const float* Y = (const float*)d_in[1];
    float* out = (float*)d_out;

    // workspace layout (ws >= 64 MB):
    //   [0, 38.8 MB)        Wd  : bf16 W, anti-diagonal-major [b][w][s<592][t]
    //   [40 MB, +4 MB)      Xp  : packed bf16 X fragments
    //   [44 MB, +4 MB)      Yp  : packed bf16 Y fragments
    //   [48 MB, +128 KB)    nx  : fp32 row norms of X
    //   [+128 KB, +256 KB)  ny  : fp32 row norms of Y
    char* ws = (char*)d_ws;
    uint2* Wd = (uint2*)ws;
    unsigned short* Xp = (unsigned short*)(ws + 41943040);
    unsigned short* Yp = (unsigned short*)(ws + 41943040 + 4194304);
    float* nx = (float*)(ws + 41943040 + 2 * 4194304);
    float* ny = (float*)(ws + 41943040 + 2 * 4194304 + 131072);

    pack_kernel<<<dim3(NB * NN / 256, 2), 256, 0, stream>>>(X, Y, Xp, Yp, nx, ny);
    cdist_kernel<<<dim3(4, 4, NB), 256, 0, stream>>>(Xp, Yp, nx, ny, Wd);
    dtw_kernel<<<NB, 128, 0, stream>>>(Wd, out);
}